// Round 1
// baseline (599.504 us; speedup 1.0000x reference)
//
#include <hip/hip_runtime.h>
#include <hip/hip_bf16.h>
#include <stdint.h>

#define DEVI __device__ __forceinline__

namespace {

constexpr int B = 8, T = 2048, C = 3, E = 256, KW = 15, BN = 32;
constexpr float EPS = 1e-5f;

// padded time layouts so dilated convs need no bounds checks
constexpr int XPAD = 8;              // conv_in reach: +/-7
constexpr int XS   = T + 2*XPAD;     // 2064
constexpr int HPAD = 224;            // max reach: 7*32
constexpr int HS   = T + 2*HPAD;     // 2496

// workspace layout (floats)
constexpr size_t O_MEAN = 0;
constexpr size_t O_STD  = 32;
constexpr size_t O_QN   = 64;
constexpr size_t XBUF   = (size_t)B*C*XS;        // 49536
constexpr size_t O_KN   = O_QN + XBUF;
constexpr size_t HBUF   = (size_t)3*B*BN*HS;     // 1,916,928 (3 nets)
constexpr size_t O_HA   = O_KN + XBUF;
constexpr size_t O_HB   = O_HA + HBUF;
constexpr size_t QBUF   = (size_t)B*T*E;         // 4,194,304
constexpr size_t O_Q    = O_HB + HBUF;           // also = zero-fill extent
constexpr size_t O_K    = O_Q + QBUF;
constexpr size_t O_V    = O_K + QBUF;            // end = O_V+QBUF ~ 66 MB

typedef __attribute__((ext_vector_type(8))) short bfrag;
typedef __attribute__((ext_vector_type(4))) float f32x4;

DEVI short f2bf(float f){            // fp32 -> bf16 bits, round-to-nearest-even
  uint32_t u = __builtin_bit_cast(uint32_t, f);
  u = u + 0x7fffu + ((u >> 16) & 1u);
  return (short)(u >> 16);
}

__global__ __launch_bounds__(256) void k_zero(float4* __restrict__ p, int n4){
  const float4 z4 = {0.f,0.f,0.f,0.f};
  for (int i = blockIdx.x*256 + threadIdx.x; i < n4; i += gridDim.x*256) p[i] = z4;
}

__global__ __launch_bounds__(256) void k_stats(const float* __restrict__ key_in,
                                               float* __restrict__ meanp, float* __restrict__ stdp){
  const int bc = blockIdx.x;           // b*C + c
  const int b = bc / C, c = bc % C;
  float s = 0.f, s2 = 0.f;
  for (int t = threadIdx.x; t < T; t += 256){
    float v = key_in[((size_t)(b*T) + t)*C + c];
    s += v; s2 += v*v;
  }
  __shared__ float r1[256], r2[256];
  r1[threadIdx.x] = s; r2[threadIdx.x] = s2;
  __syncthreads();
  for (int st = 128; st > 0; st >>= 1){
    if (threadIdx.x < st){ r1[threadIdx.x] += r1[threadIdx.x+st]; r2[threadIdx.x] += r2[threadIdx.x+st]; }
    __syncthreads();
  }
  if (threadIdx.x == 0){
    float m = r1[0] / (float)T;
    float var = r2[0] / (float)T - m*m;
    meanp[bc] = m;
    stdp[bc]  = sqrtf(var + EPS);
  }
}

__global__ __launch_bounds__(256) void k_norm(const float* __restrict__ query_in, const float* __restrict__ key_in,
                                              const float* __restrict__ revin_w, const float* __restrict__ revin_b,
                                              const float* __restrict__ meanp, const float* __restrict__ stdp,
                                              float* __restrict__ qn, float* __restrict__ kn){
  int idx = blockIdx.x*256 + threadIdx.x;   // < B*C*T
  int t = idx % T; int bc = idx / T;
  int c = bc % C;  int b = bc / C;
  float m = meanp[b*C + c];
  float inv = 1.f / stdp[b*C + c];
  float wv = revin_w[c], bv = revin_b[c];
  size_t src = ((size_t)(b*T) + t)*C + c;
  size_t dst = ((size_t)(b*C) + c)*XS + XPAD + t;
  qn[dst] = (query_in[src] - m) * inv * wv + bv;
  kn[dst] = (key_in[src]   - m) * inv * wv + bv;
}

// conv in: C=3 -> BN=32, k=15, dil=1, ReLU.  grid = 3*B*BN, block handles one (net,b,o) row.
__global__ __launch_bounds__(256) void k_conv_in(
    const float* __restrict__ qn, const float* __restrict__ kn,
    const float* __restrict__ wq, const float* __restrict__ bq,
    const float* __restrict__ wk, const float* __restrict__ bk,
    const float* __restrict__ wv, const float* __restrict__ bv,
    float* __restrict__ hout){
  __shared__ float xs[C*XS];     // whole padded input for this b (24.2 KB)
  __shared__ float wsh[C*KW];
  const int net = blockIdx.x / (B*BN);
  const int rem = blockIdx.x % (B*BN);
  const int b = rem / BN, o = rem % BN;
  const float* x    = (net==0 ? qn : kn) + (size_t)b*C*XS;
  const float* w    = (net==0 ? wq : (net==1 ? wk : wv)) + o*C*KW;
  const float* bias = (net==0 ? bq : (net==1 ? bk : bv));
  for (int i = threadIdx.x; i < C*XS; i += 256) xs[i] = x[i];
  if (threadIdx.x < C*KW) wsh[threadIdx.x] = w[threadIdx.x];
  __syncthreads();
  const float bo = bias[o];
  float* orow = hout + (((size_t)(net*B + b))*BN + o)*HS + HPAD;
  for (int j = 0; j < 8; j++){
    int t = j*256 + threadIdx.x;
    float acc = bo;
    #pragma unroll
    for (int c = 0; c < C; c++)
      #pragma unroll
      for (int kk = 0; kk < KW; kk++)
        acc += xs[c*XS + XPAD + t + kk - 7] * wsh[c*KW + kk];
    orow[t] = fmaxf(acc, 0.f);
  }
}

// dilated conv BN->BN, k=15, ReLU.  grid = 3*128: (net, b, t-tile 128).
// thread = 4 out-channels x 4 t, weights LDS-transposed [i*15+kk][o] for ds_read_b128.
__global__ __launch_bounds__(256) void k_conv_mid(
    const float* __restrict__ hin, float* __restrict__ hout,
    const float* __restrict__ wq, const float* __restrict__ wk, const float* __restrict__ wv,
    const float* __restrict__ bq, const float* __restrict__ bk, const float* __restrict__ bv,
    int layer, int dil){
  __shared__ float wt[BN*KW*BN];   // 61440 B
  const int net = blockIdx.x >> 7;
  const int rem = blockIdx.x & 127;
  const int b = rem >> 4, tt = rem & 15;
  const float* w    = (net==0 ? wq : (net==1 ? wk : wv)) + (size_t)layer*BN*BN*KW;
  const float* bias = (net==0 ? bq : (net==1 ? bk : bv)) + layer*BN;
  for (int i = threadIdx.x; i < BN*BN*KW; i += 256){
    int o = i / (BN*KW), ikk = i % (BN*KW);
    wt[ikk*BN + o] = w[i];
  }
  __syncthreads();
  const int og = threadIdx.x >> 5, ts = threadIdx.x & 31;
  float acc[4][4];
  #pragma unroll
  for (int rr = 0; rr < 4; rr++){
    float bb = bias[og*4 + rr];
    #pragma unroll
    for (int x = 0; x < 4; x++) acc[rr][x] = bb;
  }
  const float* xin = hin + ((size_t)(net*B + b))*BN*HS + HPAD + tt*128 + ts*4 - 7*dil;
  for (int i = 0; i < BN; i++){
    const float* rowp = xin + (size_t)i*HS;
    #pragma unroll
    for (int kk = 0; kk < KW; kk++){
      const float4 w4 = *(const float4*)&wt[(i*KW + kk)*BN + og*4];
      const float* pp = rowp + kk*dil;               // even offset -> 8B aligned
      float2 x01 = *(const float2*)(pp);
      float2 x23 = *(const float2*)(pp + 2);
      float xv[4] = {x01.x, x01.y, x23.x, x23.y};
      #pragma unroll
      for (int rr = 0; rr < 4; rr++){
        const float ww = (rr==0)?w4.x:((rr==1)?w4.y:((rr==2)?w4.z:w4.w));
        #pragma unroll
        for (int x = 0; x < 4; x++) acc[rr][x] += ww * xv[x];
      }
    }
  }
  #pragma unroll
  for (int rr = 0; rr < 4; rr++){
    float* op = hout + (((size_t)(net*B + b))*BN + og*4 + rr)*HS + HPAD + tt*128 + ts*4;
    float4 o4 = {fmaxf(acc[rr][0],0.f), fmaxf(acc[rr][1],0.f), fmaxf(acc[rr][2],0.f), fmaxf(acc[rr][3],0.f)};
    *(float4*)op = o4;
  }
}

// 1x1 conv BN -> E, no relu; q output pre-scaled by E^-0.5.  grid = 3*128, thread = one e.
__global__ __launch_bounds__(256) void k_conv_out(
    const float* __restrict__ hin,
    const float* __restrict__ wq, const float* __restrict__ bq,
    const float* __restrict__ wk, const float* __restrict__ bk,
    const float* __restrict__ wv, const float* __restrict__ bv,
    float* __restrict__ qo, float* __restrict__ ko, float* __restrict__ vo){
  const int net = blockIdx.x >> 7;
  const int rem = blockIdx.x & 127;
  const int b = rem >> 4, tt = rem & 15;
  const int e = threadIdx.x;
  const float* w   = (net==0 ? wq : (net==1 ? wk : wv)) + e*BN;
  const float bias = (net==0 ? bq : (net==1 ? bk : bv))[e];
  const float scale = (net==0) ? 0.0625f : 1.0f;   // E^-0.5 folded into q
  float wreg[BN];
  #pragma unroll
  for (int i = 0; i < BN; i++) wreg[i] = w[i];
  const float* hb = hin + ((size_t)(net*B + b))*BN*HS + HPAD + tt*128;
  float* outp = (net==0 ? qo : (net==1 ? ko : vo)) + ((size_t)(b*T) + tt*128)*E + e;
  for (int t2 = 0; t2 < 128; t2++){
    float acc = bias;
    #pragma unroll
    for (int i = 0; i < BN; i++) acc += hb[(size_t)i*HS + t2] * wreg[i];
    outp[(size_t)t2*E] = acc * scale;
  }
}

// flash attention (bf16 MFMA, fp32 softmax/accum) + out-proj + RevIN denorm.
// grid = B*(T/64); block = 4 waves, wave w owns q-rows [qt*64+w*16, +16).
// mfma_f32_16x16x32_bf16 layouts: A[m=lane&15][k=quad*8+j], B[k=quad*8+j][n=lane&15],
// D[row=quad*4+reg][col=lane&15]  (m89/m118-120 verified).
__global__ __launch_bounds__(256) void k_attn(
    const float* __restrict__ qbuf, const float* __restrict__ kbuf, const float* __restrict__ vbuf,
    const float* __restrict__ out_w, const float* __restrict__ out_b,
    const float* __restrict__ revin_w, const float* __restrict__ revin_b,
    const float* __restrict__ meanp, const float* __restrict__ stdp,
    float* __restrict__ out){
  __shared__ __align__(16) short Ks[32*264];    // K tile, key-major, e fast (pad 264)
  __shared__ __align__(16) short Vs[256*40];    // V tile transposed, e-major, key fast (pad 40)
  __shared__ __align__(16) short Ps[4*16*40];   // per-wave P tile, row-major [m][key]

  const int b    = blockIdx.x >> 5;
  const int qt   = blockIdx.x & 31;
  const int tid  = threadIdx.x;
  const int wave = tid >> 6;
  const int lane = tid & 63;
  const int quad = lane >> 4;
  const int l16  = lane & 15;
  const int qrow_base = qt*64 + wave*16;

  // Q A-fragments held in registers for the whole block row (8 k-steps over e)
  bfrag a_q[8];
  {
    const float* qrow = qbuf + ((size_t)(b*T) + qrow_base + l16)*E + quad*8;
    #pragma unroll
    for (int kt = 0; kt < 8; kt++){
      float4 v0 = *(const float4*)(qrow + kt*32);
      float4 v1 = *(const float4*)(qrow + kt*32 + 4);
      bfrag f;
      f[0]=f2bf(v0.x); f[1]=f2bf(v0.y); f[2]=f2bf(v0.z); f[3]=f2bf(v0.w);
      f[4]=f2bf(v1.x); f[5]=f2bf(v1.y); f[6]=f2bf(v1.z); f[7]=f2bf(v1.w);
      a_q[kt] = f;
    }
  }

  f32x4 acc_o[16];
  #pragma unroll
  for (int nt = 0; nt < 16; nt++){ f32x4 z = {0.f,0.f,0.f,0.f}; acc_o[nt] = z; }
  float m_run[4] = {-1e30f,-1e30f,-1e30f,-1e30f};
  float l_run[4] = {0.f,0.f,0.f,0.f};

  const int jk = tid >> 3;           // K staging row (0..31)
  const int e0 = (tid & 7) * 32;

  for (int kbk = 0; kbk < T/32; kbk++){
    const int j0 = kbk*32;
    // ---- stage K (key-major) + V (transposed) as bf16 ----
    {
      const float* krow = kbuf + ((size_t)(b*T) + j0 + jk)*E + e0;
      #pragma unroll
      for (int u = 0; u < 32; u += 4){
        float4 kv = *(const float4*)(krow + u);
        short* d = &Ks[jk*264 + e0 + u];
        d[0]=f2bf(kv.x); d[1]=f2bf(kv.y); d[2]=f2bf(kv.z); d[3]=f2bf(kv.w);
      }
      const float* vcol = vbuf + ((size_t)(b*T) + j0)*E + tid;
      #pragma unroll 8
      for (int j = 0; j < 32; j++)
        Vs[tid*40 + j] = f2bf(vcol[(size_t)j*E]);
    }
    __syncthreads();

    // ---- S = Q K^T (16 rows x 32 keys per wave) ----
    f32x4 sac0 = {0.f,0.f,0.f,0.f}, sac1 = {0.f,0.f,0.f,0.f};
    #pragma unroll
    for (int kt = 0; kt < 8; kt++){
      bfrag kb0 = *(const bfrag*)&Ks[(l16     )*264 + kt*32 + quad*8];
      bfrag kb1 = *(const bfrag*)&Ks[(16 + l16)*264 + kt*32 + quad*8];
      sac0 = __builtin_amdgcn_mfma_f32_16x16x32_bf16(a_q[kt], kb0, sac0, 0, 0, 0);
      sac1 = __builtin_amdgcn_mfma_f32_16x16x32_bf16(a_q[kt], kb1, sac1, 0, 0, 0);
    }

    // ---- online softmax: rows = quad*4+rr, cols = l16 / 16+l16 ----
    float mloc[4], lloc[4], p0[4], p1[4], alpha[4];
    #pragma unroll
    for (int rr = 0; rr < 4; rr++) mloc[rr] = fmaxf(sac0[rr], sac1[rr]);
    #pragma unroll
    for (int off = 1; off < 16; off <<= 1)
      #pragma unroll
      for (int rr = 0; rr < 4; rr++) mloc[rr] = fmaxf(mloc[rr], __shfl_xor(mloc[rr], off));
    #pragma unroll
    for (int rr = 0; rr < 4; rr++){
      float mn = fmaxf(m_run[rr], mloc[rr]);
      alpha[rr] = __expf(m_run[rr] - mn);
      p0[rr] = __expf(sac0[rr] - mn);
      p1[rr] = __expf(sac1[rr] - mn);
      lloc[rr] = p0[rr] + p1[rr];
      m_run[rr] = mn;
    }
    #pragma unroll
    for (int off = 1; off < 16; off <<= 1)
      #pragma unroll
      for (int rr = 0; rr < 4; rr++) lloc[rr] += __shfl_xor(lloc[rr], off);
    #pragma unroll
    for (int rr = 0; rr < 4; rr++) l_run[rr] = l_run[rr]*alpha[rr] + lloc[rr];
    // P (C-layout) -> per-wave LDS, row-major, for A-fragment re-read
    #pragma unroll
    for (int rr = 0; rr < 4; rr++){
      Ps[wave*640 + (quad*4+rr)*40 + l16]      = f2bf(p0[rr]);
      Ps[wave*640 + (quad*4+rr)*40 + 16 + l16] = f2bf(p1[rr]);
    }
    // rescale O
    #pragma unroll
    for (int nt = 0; nt < 16; nt++)
      #pragma unroll
      for (int rr = 0; rr < 4; rr++) acc_o[nt][rr] *= alpha[rr];
    __syncthreads();

    // ---- O += P V : one MFMA per 16-wide e tile, K = 32 keys ----
    bfrag pa = *(const bfrag*)&Ps[wave*640 + l16*40 + quad*8];
    #pragma unroll
    for (int nt = 0; nt < 16; nt++){
      bfrag vf = *(const bfrag*)&Vs[(nt*16 + l16)*40 + quad*8];
      acc_o[nt] = __builtin_amdgcn_mfma_f32_16x16x32_bf16(pa, vf, acc_o[nt], 0, 0, 0);
    }
    __syncthreads();
  }

  // ---- epilogue: /l, project to C=3, denorm, store ----
  #pragma unroll
  for (int rr = 0; rr < 4; rr++){
    float inv_l = 1.f / l_run[rr];
    #pragma unroll
    for (int nt = 0; nt < 16; nt++) acc_o[nt][rr] *= inv_l;
  }
  float part[3][4] = {};
  #pragma unroll
  for (int nt = 0; nt < 16; nt++){
    #pragma unroll
    for (int ch = 0; ch < 3; ch++){
      float wv = out_w[ch*E + nt*16 + l16];
      #pragma unroll
      for (int rr = 0; rr < 4; rr++) part[ch][rr] += acc_o[nt][rr] * wv;
    }
  }
  #pragma unroll
  for (int off = 1; off < 16; off <<= 1)
    #pragma unroll
    for (int ch = 0; ch < 3; ch++)
      #pragma unroll
      for (int rr = 0; rr < 4; rr++) part[ch][rr] += __shfl_xor(part[ch][rr], off);

  if (l16 == 0){
    #pragma unroll
    for (int rr = 0; rr < 4; rr++){
      int row = qrow_base + quad*4 + rr;
      #pragma unroll
      for (int ch = 0; ch < 3; ch++){
        float val = part[ch][rr] + out_b[ch];
        val = (val - revin_b[ch]) / revin_w[ch];
        val = val * stdp[b*C + ch] + meanp[b*C + ch];
        out[((size_t)(b*T) + row)*C + ch] = val;
      }
    }
  }
}

} // namespace

extern "C" void kernel_launch(void* const* d_in, const int* in_sizes, int n_in,
                              void* d_out, int out_size, void* d_ws, size_t ws_size,
                              hipStream_t stream){
  const float* query_in = (const float*)d_in[0];
  const float* key_in   = (const float*)d_in[1];
  const float* q_w_in   = (const float*)d_in[2];
  const float* q_b_in   = (const float*)d_in[3];
  const float* q_w_mid  = (const float*)d_in[4];
  const float* q_b_mid  = (const float*)d_in[5];
  const float* q_w_out  = (const float*)d_in[6];
  const float* q_b_out  = (const float*)d_in[7];
  const float* k_w_in   = (const float*)d_in[8];
  const float* k_b_in   = (const float*)d_in[9];
  const float* k_w_mid  = (const float*)d_in[10];
  const float* k_b_mid  = (const float*)d_in[11];
  const float* k_w_out  = (const float*)d_in[12];
  const float* k_b_out  = (const float*)d_in[13];
  const float* v_w_in   = (const float*)d_in[14];
  const float* v_b_in   = (const float*)d_in[15];
  const float* v_w_mid  = (const float*)d_in[16];
  const float* v_b_mid  = (const float*)d_in[17];
  const float* v_w_out  = (const float*)d_in[18];
  const float* v_b_out  = (const float*)d_in[19];
  const float* out_w    = (const float*)d_in[20];
  const float* out_b    = (const float*)d_in[21];
  const float* revin_w  = (const float*)d_in[22];
  const float* revin_b  = (const float*)d_in[23];
  float* ws  = (float*)d_ws;
  float* out = (float*)d_out;

  // zero stats/xn/h buffers (pads must be 0; ws is poisoned each call)
  hipLaunchKernelGGL(k_zero, dim3(2048), dim3(256), 0, stream, (float4*)ws, (int)(O_Q/4));
  hipLaunchKernelGGL(k_stats, dim3(B*C), dim3(256), 0, stream, key_in, ws+O_MEAN, ws+O_STD);
  hipLaunchKernelGGL(k_norm, dim3((B*C*T)/256), dim3(256), 0, stream,
                     query_in, key_in, revin_w, revin_b, ws+O_MEAN, ws+O_STD, ws+O_QN, ws+O_KN);
  hipLaunchKernelGGL(k_conv_in, dim3(3*B*BN), dim3(256), 0, stream,
                     ws+O_QN, ws+O_KN, q_w_in, q_b_in, k_w_in, k_b_in, v_w_in, v_b_in, ws+O_HA);
  float* ha = ws + O_HA;
  float* hb = ws + O_HB;
  int dil = 2;
  for (int layer = 0; layer < 5; layer++){
    hipLaunchKernelGGL(k_conv_mid, dim3(3*128), dim3(256), 0, stream,
                       ha, hb, q_w_mid, k_w_mid, v_w_mid, q_b_mid, k_b_mid, v_b_mid, layer, dil);
    float* tmp = ha; ha = hb; hb = tmp;
    dil <<= 1;
  }
  hipLaunchKernelGGL(k_conv_out, dim3(3*128), dim3(256), 0, stream,
                     ha, q_w_out, q_b_out, k_w_out, k_b_out, v_w_out, v_b_out,
                     ws+O_Q, ws+O_K, ws+O_V);
  hipLaunchKernelGGL(k_attn, dim3(B*(T/64)), dim3(256), 0, stream,
                     ws+O_Q, ws+O_K, ws+O_V, out_w, out_b, revin_w, revin_b,
                     ws+O_MEAN, ws+O_STD, out);
}

// Round 2
// 506.986 us; speedup vs baseline: 1.1825x; 1.1825x over previous
//
#include <hip/hip_runtime.h>
#include <hip/hip_bf16.h>
#include <stdint.h>

#define DEVI __device__ __forceinline__

namespace {

constexpr int B = 8, T = 2048, C = 3, E = 256, KW = 15, BN = 32;
constexpr float EPS = 1e-5f;

// padded time layouts so dilated convs need no bounds checks
constexpr int XPAD = 8;              // conv_in reach: +/-7
constexpr int XS   = T + 2*XPAD;     // 2064
constexpr int HPAD = 224;            // max reach: 7*32
constexpr int HS   = T + 2*HPAD;     // 2496

// workspace layout (float units)
constexpr size_t O_MEAN = 0;
constexpr size_t O_STD  = 32;
constexpr size_t O_QN   = 64;
constexpr size_t XBUF   = (size_t)B*C*XS;        // 49536
constexpr size_t O_KN   = O_QN + XBUF;
constexpr size_t HBUF   = (size_t)3*B*BN*HS;     // 1,916,928 per buffer (3 nets)
constexpr size_t O_HA   = O_KN + XBUF;
constexpr size_t O_HB   = O_HA + HBUF;
constexpr size_t O_Q    = O_HB + HBUF;           // zero-fill extent ends here
constexpr size_t QBUF_H = (size_t)B*T*E/2;       // bf16 buffer in float units
constexpr size_t O_K    = O_Q + QBUF_H;
constexpr size_t O_V    = O_K + QBUF_H;
constexpr size_t O_PO   = O_V + QBUF_H;          // 2 splits x B*T*E bf16 = B*T*E float units
constexpr size_t O_ML   = O_PO + (size_t)B*T*E;  // m[2*B*T] then l[2*B*T]
// total = O_ML + 4*B*T = 14,484,288 floats = 57.9 MB (round1 used 66 MB OK)

typedef __attribute__((ext_vector_type(8))) short bfrag;
typedef __attribute__((ext_vector_type(4))) float f32x4;

DEVI short f2bf(float f){            // fp32 -> bf16 bits, round-to-nearest-even
  uint32_t u = __builtin_bit_cast(uint32_t, f);
  u = u + 0x7fffu + ((u >> 16) & 1u);
  return (short)(u >> 16);
}
DEVI float bf2f(unsigned short u){
  uint32_t x = (uint32_t)u << 16;
  return __builtin_bit_cast(float, x);
}

__global__ __launch_bounds__(256) void k_zero(float4* __restrict__ p, int n4){
  const float4 z4 = {0.f,0.f,0.f,0.f};
  for (int i = blockIdx.x*256 + threadIdx.x; i < n4; i += gridDim.x*256) p[i] = z4;
}

__global__ __launch_bounds__(256) void k_stats(const float* __restrict__ key_in,
                                               float* __restrict__ meanp, float* __restrict__ stdp){
  const int bc = blockIdx.x;           // b*C + c
  const int b = bc / C, c = bc % C;
  float s = 0.f, s2 = 0.f;
  for (int t = threadIdx.x; t < T; t += 256){
    float v = key_in[((size_t)(b*T) + t)*C + c];
    s += v; s2 += v*v;
  }
  __shared__ float r1[256], r2[256];
  r1[threadIdx.x] = s; r2[threadIdx.x] = s2;
  __syncthreads();
  for (int st = 128; st > 0; st >>= 1){
    if (threadIdx.x < st){ r1[threadIdx.x] += r1[threadIdx.x+st]; r2[threadIdx.x] += r2[threadIdx.x+st]; }
    __syncthreads();
  }
  if (threadIdx.x == 0){
    float m = r1[0] / (float)T;
    float var = r2[0] / (float)T - m*m;
    meanp[bc] = m;
    stdp[bc]  = sqrtf(var + EPS);
  }
}

__global__ __launch_bounds__(256) void k_norm(const float* __restrict__ query_in, const float* __restrict__ key_in,
                                              const float* __restrict__ revin_w, const float* __restrict__ revin_b,
                                              const float* __restrict__ meanp, const float* __restrict__ stdp,
                                              float* __restrict__ qn, float* __restrict__ kn){
  int idx = blockIdx.x*256 + threadIdx.x;   // < B*C*T
  int t = idx % T; int bc = idx / T;
  int c = bc % C;  int b = bc / C;
  float m = meanp[b*C + c];
  float inv = 1.f / stdp[b*C + c];
  float wv = revin_w[c], bv = revin_b[c];
  size_t src = ((size_t)(b*T) + t)*C + c;
  size_t dst = ((size_t)(b*C) + c)*XS + XPAD + t;
  qn[dst] = (query_in[src] - m) * inv * wv + bv;
  kn[dst] = (key_in[src]   - m) * inv * wv + bv;
}

// conv in: C=3 -> BN=32, k=15, dil=1, ReLU.  grid = 3*B*BN, block = one (net,b,o) row.
__global__ __launch_bounds__(256) void k_conv_in(
    const float* __restrict__ qn, const float* __restrict__ kn,
    const float* __restrict__ wq, const float* __restrict__ bq,
    const float* __restrict__ wk, const float* __restrict__ bk,
    const float* __restrict__ wv, const float* __restrict__ bv,
    float* __restrict__ hout){
  __shared__ float xs[C*XS];
  __shared__ float wsh[C*KW];
  const int net = blockIdx.x / (B*BN);
  const int rem = blockIdx.x % (B*BN);
  const int b = rem / BN, o = rem % BN;
  const float* x    = (net==0 ? qn : kn) + (size_t)b*C*XS;
  const float* w    = (net==0 ? wq : (net==1 ? wk : wv)) + o*C*KW;
  const float* bias = (net==0 ? bq : (net==1 ? bk : bv));
  for (int i = threadIdx.x; i < C*XS; i += 256) xs[i] = x[i];
  if (threadIdx.x < C*KW) wsh[threadIdx.x] = w[threadIdx.x];
  __syncthreads();
  const float bo = bias[o];
  float* orow = hout + (((size_t)(net*B + b))*BN + o)*HS + HPAD;
  for (int j = 0; j < 8; j++){
    int t = j*256 + threadIdx.x;
    float acc = bo;
    #pragma unroll
    for (int c = 0; c < C; c++)
      #pragma unroll
      for (int kk = 0; kk < KW; kk++)
        acc += xs[c*XS + XPAD + t + kk - 7] * wsh[c*KW + kk];
    orow[t] = fmaxf(acc, 0.f);
  }
}

// dilated conv BN->BN, k=15, ReLU.
// grid = 3*8*16*2 = 768: (net, b, ttile of 128, o-half of 16).
// wave -> o-octet (wave-uniform => weight ds_read_b128 is a broadcast), lane -> t.
__global__ __launch_bounds__(256) void k_conv_mid(
    const float* __restrict__ hin, float* __restrict__ hout,
    const float* __restrict__ wq, const float* __restrict__ wk, const float* __restrict__ wv,
    const float* __restrict__ bq, const float* __restrict__ bk, const float* __restrict__ bv,
    int layer, int dil){
  __shared__ float wt[BN*KW*16];   // [i*15+kk][o16] = 30720 B
  const int net = blockIdx.x >> 8;          // /256
  const int rem = blockIdx.x & 255;
  const int b = rem >> 5;
  const int tt = (rem & 31) >> 1;
  const int oh = rem & 1;
  const float* w    = (net==0 ? wq : (net==1 ? wk : wv)) + (size_t)layer*BN*BN*KW;
  const float* bias = (net==0 ? bq : (net==1 ? bk : bv)) + layer*BN;
  for (int idx = threadIdx.x; idx < BN*KW*16; idx += 256){
    int o_l = idx & 15, ikk = idx >> 4;
    wt[idx] = w[(size_t)(oh*16 + o_l)*BN*KW + ikk];
  }
  __syncthreads();
  const int wave = threadIdx.x >> 6;
  const int lane = threadIdx.x & 63;
  const int octet = wave & 1;               // o sub-octet within the 16
  const int t = tt*128 + (wave>>1)*64 + lane;
  float acc[8];
  #pragma unroll
  for (int r = 0; r < 8; r++) acc[r] = 0.f;
  const float* xin = hin + (((size_t)(net*B + b))*BN)*HS + HPAD + t - 7*dil;
  for (int i = 0; i < BN; i++){
    const float* xr = xin + (size_t)i*HS;
    #pragma unroll
    for (int kk = 0; kk < KW; kk++){
      const float4 wA = *(const float4*)&wt[(i*KW + kk)*16 + octet*8];
      const float4 wB = *(const float4*)&wt[(i*KW + kk)*16 + octet*8 + 4];
      const float xv = xr[kk*dil];
      acc[0] += wA.x*xv; acc[1] += wA.y*xv; acc[2] += wA.z*xv; acc[3] += wA.w*xv;
      acc[4] += wB.x*xv; acc[5] += wB.y*xv; acc[6] += wB.z*xv; acc[7] += wB.w*xv;
    }
  }
  #pragma unroll
  for (int r = 0; r < 8; r++){
    const int o_g = oh*16 + octet*8 + r;
    float v = fmaxf(acc[r] + bias[o_g], 0.f);
    hout[(((size_t)(net*B + b))*BN + o_g)*HS + HPAD + t] = v;
  }
}

// 1x1 conv BN -> E, write bf16; q pre-scaled by E^-0.5.
// grid = 3*8*16*4 = 1536: (net, b, ttile 128, e-quarter 64). wave -> 16-e group (uniform).
__global__ __launch_bounds__(256) void k_conv_out(
    const float* __restrict__ hin,
    const float* __restrict__ wq, const float* __restrict__ bq,
    const float* __restrict__ wk, const float* __restrict__ bk,
    const float* __restrict__ wv, const float* __restrict__ bv,
    unsigned short* __restrict__ qo, unsigned short* __restrict__ ko, unsigned short* __restrict__ vo){
  __shared__ float wsh[BN*64];   // [i][e64] = 8 KB
  const int net = blockIdx.x >> 9;          // /512
  const int rem = blockIdx.x & 511;
  const int b = rem >> 6;
  const int tt = (rem & 63) >> 2;
  const int eq = rem & 3;
  const float* w    = (net==0 ? wq : (net==1 ? wk : wv));
  const float* bias = (net==0 ? bq : (net==1 ? bk : bv));
  for (int idx = threadIdx.x; idx < BN*64; idx += 256){
    int el = idx & 63, i = idx >> 6;
    wsh[idx] = w[(size_t)(eq*64 + el)*BN + i];
  }
  __syncthreads();
  const int wave = threadIdx.x >> 6;
  const int lane = threadIdx.x & 63;
  const int t0 = tt*128 + lane*2;
  float acc[16][2];
  #pragma unroll
  for (int j = 0; j < 16; j++){ acc[j][0] = 0.f; acc[j][1] = 0.f; }
  const float* hb = hin + (((size_t)(net*B + b))*BN)*HS + HPAD + t0;
  for (int i = 0; i < BN; i++){
    const float2 xv = *(const float2*)(hb + (size_t)i*HS);
    #pragma unroll
    for (int u = 0; u < 4; u++){
      const float4 w4 = *(const float4*)&wsh[i*64 + wave*16 + u*4];
      acc[u*4+0][0] += w4.x*xv.x; acc[u*4+0][1] += w4.x*xv.y;
      acc[u*4+1][0] += w4.y*xv.x; acc[u*4+1][1] += w4.y*xv.y;
      acc[u*4+2][0] += w4.z*xv.x; acc[u*4+2][1] += w4.z*xv.y;
      acc[u*4+3][0] += w4.w*xv.x; acc[u*4+3][1] += w4.w*xv.y;
    }
  }
  const int e_base = eq*64 + wave*16;
  const float scale = (net==0) ? 0.0625f : 1.0f;
  unsigned short* outp = (net==0 ? qo : (net==1 ? ko : vo));
  #pragma unroll
  for (int z = 0; z < 2; z++){
    bfrag pk[2];
    #pragma unroll
    for (int j = 0; j < 16; j++)
      pk[j>>3][j&7] = f2bf((acc[j][z] + bias[e_base + j]) * scale);
    size_t dst = ((size_t)(b*T) + t0 + z)*E + e_base;
    *(bfrag*)&outp[dst]     = pk[0];
    *(bfrag*)&outp[dst + 8] = pk[1];
  }
}

// flash attention, split-K=2. grid = B*32*2; block = 4 waves, wave w: q-rows [qt*64+w*16,+16).
// partial O (normalized, bf16) + m,l to global; combine kernel merges + projects + denorms.
// mfma_f32_16x16x32_bf16: A[m=l16][k=quad*8+j], B[k=quad*8+j][n=l16], D[row=quad*4+reg][col=l16].
__global__ __launch_bounds__(256) void k_attn(
    const unsigned short* __restrict__ qbuf, const unsigned short* __restrict__ kbuf,
    const unsigned short* __restrict__ vbuf,
    unsigned short* __restrict__ PO, float* __restrict__ MLm, float* __restrict__ MLl){
  __shared__ __align__(16) short Ks[32*264];    // K tile, key-major, e fast
  __shared__ __align__(16) short Vs[256*40];    // V^T tile, e-major, key fast
  __shared__ __align__(16) short Ps[4*16*40];   // per-wave P tile, row-major [q][key]

  const int s    = blockIdx.x & 1;
  const int qt   = (blockIdx.x >> 1) & 31;
  const int b    = blockIdx.x >> 6;
  const int tid  = threadIdx.x;
  const int wave = tid >> 6;
  const int lane = tid & 63;
  const int quad = lane >> 4;
  const int l16  = lane & 15;
  const int qrow_base = qt*64 + wave*16;

  bfrag a_q[8];
  {
    const unsigned short* qrow = qbuf + ((size_t)(b*T) + qrow_base + l16)*E + quad*8;
    #pragma unroll
    for (int kt = 0; kt < 8; kt++)
      a_q[kt] = *(const bfrag*)&qrow[kt*32];
  }

  f32x4 acc_o[16];
  #pragma unroll
  for (int nt = 0; nt < 16; nt++){ f32x4 z = {0.f,0.f,0.f,0.f}; acc_o[nt] = z; }
  float m_run[4] = {-1e30f,-1e30f,-1e30f,-1e30f};
  float l_run[4] = {0.f,0.f,0.f,0.f};

  const int jk = tid >> 3;           // K staging row 0..31
  const int ec = (tid & 7) * 32;     // e chunk

  for (int kbk = s*32; kbk < s*32 + 32; kbk++){
    const int j0 = kbk*32;
    // stage K rows (vector copy) and V columns (gather + packed b128 writes)
    {
      const unsigned short* krow = kbuf + ((size_t)(b*T) + j0 + jk)*E + ec;
      #pragma unroll
      for (int u = 0; u < 4; u++)
        *(bfrag*)&Ks[jk*264 + ec + u*8] = *(const bfrag*)&krow[u*8];
      const unsigned short* vcol = vbuf + ((size_t)(b*T) + j0)*E + tid;
      unsigned short tmp[32];
      #pragma unroll
      for (int j = 0; j < 32; j++) tmp[j] = vcol[(size_t)j*E];
      #pragma unroll
      for (int u = 0; u < 4; u++){
        bfrag p;
        #pragma unroll
        for (int z = 0; z < 8; z++) p[z] = (short)tmp[u*8+z];
        *(bfrag*)&Vs[tid*40 + u*8] = p;
      }
    }
    __syncthreads();

    // S = Q K^T
    f32x4 sac0 = {0.f,0.f,0.f,0.f}, sac1 = {0.f,0.f,0.f,0.f};
    #pragma unroll
    for (int kt = 0; kt < 8; kt++){
      bfrag kb0 = *(const bfrag*)&Ks[(l16     )*264 + kt*32 + quad*8];
      bfrag kb1 = *(const bfrag*)&Ks[(16 + l16)*264 + kt*32 + quad*8];
      sac0 = __builtin_amdgcn_mfma_f32_16x16x32_bf16(a_q[kt], kb0, sac0, 0, 0, 0);
      sac1 = __builtin_amdgcn_mfma_f32_16x16x32_bf16(a_q[kt], kb1, sac1, 0, 0, 0);
    }

    // online softmax (rows = quad*4+rr, cols = l16 / 16+l16)
    float mloc[4], lloc[4], p0[4], p1[4], alpha[4];
    #pragma unroll
    for (int rr = 0; rr < 4; rr++) mloc[rr] = fmaxf(sac0[rr], sac1[rr]);
    #pragma unroll
    for (int off = 1; off < 16; off <<= 1)
      #pragma unroll
      for (int rr = 0; rr < 4; rr++) mloc[rr] = fmaxf(mloc[rr], __shfl_xor(mloc[rr], off));
    #pragma unroll
    for (int rr = 0; rr < 4; rr++){
      float mn = fmaxf(m_run[rr], mloc[rr]);
      alpha[rr] = __expf(m_run[rr] - mn);
      p0[rr] = __expf(sac0[rr] - mn);
      p1[rr] = __expf(sac1[rr] - mn);
      lloc[rr] = p0[rr] + p1[rr];
      m_run[rr] = mn;
    }
    #pragma unroll
    for (int off = 1; off < 16; off <<= 1)
      #pragma unroll
      for (int rr = 0; rr < 4; rr++) lloc[rr] += __shfl_xor(lloc[rr], off);
    #pragma unroll
    for (int rr = 0; rr < 4; rr++) l_run[rr] = l_run[rr]*alpha[rr] + lloc[rr];
    // P -> per-wave LDS (no barrier needed: same wave writes & reads)
    #pragma unroll
    for (int rr = 0; rr < 4; rr++){
      Ps[wave*640 + (quad*4+rr)*40 + l16]      = f2bf(p0[rr]);
      Ps[wave*640 + (quad*4+rr)*40 + 16 + l16] = f2bf(p1[rr]);
    }
    #pragma unroll
    for (int nt = 0; nt < 16; nt++)
      #pragma unroll
      for (int rr = 0; rr < 4; rr++) acc_o[nt][rr] *= alpha[rr];

    // O += P V
    bfrag pa = *(const bfrag*)&Ps[wave*640 + l16*40 + quad*8];
    #pragma unroll
    for (int nt = 0; nt < 16; nt++){
      bfrag vf = *(const bfrag*)&Vs[(nt*16 + l16)*40 + quad*8];
      acc_o[nt] = __builtin_amdgcn_mfma_f32_16x16x32_bf16(pa, vf, acc_o[nt], 0, 0, 0);
    }
    __syncthreads();
  }

  // epilogue: store normalized partial O (bf16) + m,l
  const size_t pbase = ((size_t)(s*B + b))*T;
  #pragma unroll
  for (int rr = 0; rr < 4; rr++){
    float inv_l = 1.f / l_run[rr];
    const size_t row = pbase + qrow_base + quad*4 + rr;
    #pragma unroll
    for (int nt = 0; nt < 16; nt++)
      PO[row*E + nt*16 + l16] = (unsigned short)f2bf(acc_o[nt][rr] * inv_l);
    if (l16 == 0){
      MLm[row] = m_run[rr];
      MLl[row] = l_run[rr];
    }
  }
}

// combine splits + out-projection + RevIN denorm. grid = B*T/64, 256 threads.
__global__ __launch_bounds__(256) void k_comb(
    const unsigned short* __restrict__ PO, const float* __restrict__ MLm, const float* __restrict__ MLl,
    const float* __restrict__ out_w, const float* __restrict__ out_b,
    const float* __restrict__ revin_w, const float* __restrict__ revin_b,
    const float* __restrict__ meanp, const float* __restrict__ stdp,
    float* __restrict__ out){
  __shared__ float wsh[3*E];
  for (int i = threadIdx.x; i < 3*E; i += 256) wsh[i] = out_w[i];
  __syncthreads();
  const int b  = blockIdx.x >> 5;
  const int rt = blockIdx.x & 31;
  const int row = rt*64 + (threadIdx.x >> 2);
  const int c4 = threadIdx.x & 3;
  const int e0 = c4*64;
  const size_t base0 = ((size_t)b)*T + row;
  const size_t base1 = ((size_t)(B + b))*T + row;
  float m0 = MLm[base0], m1 = MLm[base1];
  float l0 = MLl[base0], l1 = MLl[base1];
  float mx = fmaxf(m0, m1);
  float w0 = __expf(m0 - mx)*l0, w1 = __expf(m1 - mx)*l1;
  float inv = 1.f/(w0 + w1);
  w0 *= inv; w1 *= inv;
  const unsigned short* p0 = PO + base0*E + e0;
  const unsigned short* p1 = PO + base1*E + e0;
  float pr[3] = {0.f, 0.f, 0.f};
  #pragma unroll
  for (int u = 0; u < 8; u++){
    bfrag a0 = *(const bfrag*)&p0[u*8];
    bfrag a1 = *(const bfrag*)&p1[u*8];
    #pragma unroll
    for (int z = 0; z < 8; z++){
      float v = w0*bf2f((unsigned short)a0[z]) + w1*bf2f((unsigned short)a1[z]);
      int e = e0 + u*8 + z;
      pr[0] += v*wsh[e];
      pr[1] += v*wsh[E + e];
      pr[2] += v*wsh[2*E + e];
    }
  }
  #pragma unroll
  for (int c = 0; c < 3; c++){
    pr[c] += __shfl_xor(pr[c], 1);
    pr[c] += __shfl_xor(pr[c], 2);
  }
  if (c4 == 0){
    #pragma unroll
    for (int c = 0; c < 3; c++){
      float val = pr[c] + out_b[c];
      val = (val - revin_b[c]) / revin_w[c];
      val = val * stdp[b*C + c] + meanp[b*C + c];
      out[((size_t)(b*T) + row)*C + c] = val;
    }
  }
}

} // namespace

extern "C" void kernel_launch(void* const* d_in, const int* in_sizes, int n_in,
                              void* d_out, int out_size, void* d_ws, size_t ws_size,
                              hipStream_t stream){
  const float* query_in = (const float*)d_in[0];
  const float* key_in   = (const float*)d_in[1];
  const float* q_w_in   = (const float*)d_in[2];
  const float* q_b_in   = (const float*)d_in[3];
  const float* q_w_mid  = (const float*)d_in[4];
  const float* q_b_mid  = (const float*)d_in[5];
  const float* q_w_out  = (const float*)d_in[6];
  const float* q_b_out  = (const float*)d_in[7];
  const float* k_w_in   = (const float*)d_in[8];
  const float* k_b_in   = (const float*)d_in[9];
  const float* k_w_mid  = (const float*)d_in[10];
  const float* k_b_mid  = (const float*)d_in[11];
  const float* k_w_out  = (const float*)d_in[12];
  const float* k_b_out  = (const float*)d_in[13];
  const float* v_w_in   = (const float*)d_in[14];
  const float* v_b_in   = (const float*)d_in[15];
  const float* v_w_mid  = (const float*)d_in[16];
  const float* v_b_mid  = (const float*)d_in[17];
  const float* v_w_out  = (const float*)d_in[18];
  const float* v_b_out  = (const float*)d_in[19];
  const float* out_w    = (const float*)d_in[20];
  const float* out_b    = (const float*)d_in[21];
  const float* revin_w  = (const float*)d_in[22];
  const float* revin_b  = (const float*)d_in[23];
  float* ws  = (float*)d_ws;
  float* out = (float*)d_out;

  unsigned short* qb = (unsigned short*)(ws + O_Q);
  unsigned short* kb = (unsigned short*)(ws + O_K);
  unsigned short* vb = (unsigned short*)(ws + O_V);
  unsigned short* PO = (unsigned short*)(ws + O_PO);
  float* MLm = ws + O_ML;
  float* MLl = ws + O_ML + 2*(size_t)B*T;

  hipLaunchKernelGGL(k_zero, dim3(2048), dim3(256), 0, stream, (float4*)ws, (int)(O_Q/4));
  hipLaunchKernelGGL(k_stats, dim3(B*C), dim3(256), 0, stream, key_in, ws+O_MEAN, ws+O_STD);
  hipLaunchKernelGGL(k_norm, dim3((B*C*T)/256), dim3(256), 0, stream,
                     query_in, key_in, revin_w, revin_b, ws+O_MEAN, ws+O_STD, ws+O_QN, ws+O_KN);
  hipLaunchKernelGGL(k_conv_in, dim3(3*B*BN), dim3(256), 0, stream,
                     ws+O_QN, ws+O_KN, q_w_in, q_b_in, k_w_in, k_b_in, v_w_in, v_b_in, ws+O_HA);
  float* ha = ws + O_HA;
  float* hb = ws + O_HB;
  int dil = 2;
  for (int layer = 0; layer < 5; layer++){
    hipLaunchKernelGGL(k_conv_mid, dim3(768), dim3(256), 0, stream,
                       ha, hb, q_w_mid, k_w_mid, v_w_mid, q_b_mid, k_b_mid, v_b_mid, layer, dil);
    float* tmp = ha; ha = hb; hb = tmp;
    dil <<= 1;
  }
  hipLaunchKernelGGL(k_conv_out, dim3(1536), dim3(256), 0, stream,
                     ha, q_w_out, q_b_out, k_w_out, k_b_out, v_w_out, v_b_out, qb, kb, vb);
  hipLaunchKernelGGL(k_attn, dim3(B*32*2), dim3(256), 0, stream, qb, kb, vb, PO, MLm, MLl);
  hipLaunchKernelGGL(k_comb, dim3(B*T/64), dim3(256), 0, stream,
                     PO, MLm, MLl, out_w, out_b, revin_w, revin_b, ws+O_MEAN, ws+O_STD, out);
}

// Round 3
// 505.306 us; speedup vs baseline: 1.1864x; 1.0033x over previous
//
#include <hip/hip_runtime.h>
#include <hip/hip_bf16.h>
#include <stdint.h>

#define DEVI __device__ __forceinline__

namespace {

constexpr int B = 8, T = 2048, C = 3, E = 256, KW = 15, BN = 32;
constexpr float EPS = 1e-5f;

constexpr int XPAD = 8;              // conv_in reach: +/-7
constexpr int XS   = T + 2*XPAD;     // 2064
constexpr int HPAD = 224;            // max reach: 7*32
constexpr int HS   = T + 2*HPAD;     // 2496

// workspace layout (float units)
constexpr size_t O_MEAN = 0;
constexpr size_t O_STD  = 32;
constexpr size_t O_QN   = 64;
constexpr size_t XBUF   = (size_t)B*C*XS;        // 49536
constexpr size_t O_KN   = O_QN + XBUF;
constexpr size_t HBUF   = (size_t)3*B*BN*HS;     // 1,916,928 per buffer
constexpr size_t O_HA   = O_KN + XBUF;
constexpr size_t O_HB   = O_HA + HBUF;
constexpr size_t O_Q    = O_HB + HBUF;           // zero-fill extent ends here (3,932,992)
constexpr size_t QBUF_H = (size_t)B*T*E/2;       // bf16 buffer in float units (2,097,152)
constexpr size_t O_K    = O_Q + QBUF_H;
constexpr size_t O_V    = O_K + QBUF_H;
constexpr size_t O_PO_HI= O_V + QBUF_H;          // splits 0..2 (3 x QBUF_H) -> end 16,515,904 fl = 66.06 MB (== round-1 extent, proven OK)
// split 3 + m/l overlay the (already-consumed) qn/kn/h region:
constexpr size_t O_PO_LO= O_QN;                  // 1 split
constexpr size_t O_MLM  = O_PO_LO + QBUF_H;      // 4*B*T floats
constexpr size_t O_MLL  = O_MLM + (size_t)4*B*T; // 4*B*T floats (end 2,228,288 < O_Q; region consumed before attn)

typedef __attribute__((ext_vector_type(8))) short bfrag;
typedef __attribute__((ext_vector_type(4))) float f32x4;

DEVI short f2bf(float f){            // fp32 -> bf16 bits, round-to-nearest-even
  uint32_t u = __builtin_bit_cast(uint32_t, f);
  u = u + 0x7fffu + ((u >> 16) & 1u);
  return (short)(u >> 16);
}
DEVI float bf2f(unsigned short u){
  uint32_t x = (uint32_t)u << 16;
  return __builtin_bit_cast(float, x);
}

__global__ __launch_bounds__(256) void k_zero(float4* __restrict__ p, int n4){
  const float4 z4 = {0.f,0.f,0.f,0.f};
  for (int i = blockIdx.x*256 + threadIdx.x; i < n4; i += gridDim.x*256) p[i] = z4;
}

__global__ __launch_bounds__(256) void k_stats(const float* __restrict__ key_in,
                                               float* __restrict__ meanp, float* __restrict__ stdp){
  const int bc = blockIdx.x;
  const int b = bc / C, c = bc % C;
  float s = 0.f, s2 = 0.f;
  for (int t = threadIdx.x; t < T; t += 256){
    float v = key_in[((size_t)(b*T) + t)*C + c];
    s += v; s2 += v*v;
  }
  __shared__ float r1[256], r2[256];
  r1[threadIdx.x] = s; r2[threadIdx.x] = s2;
  __syncthreads();
  for (int st = 128; st > 0; st >>= 1){
    if (threadIdx.x < st){ r1[threadIdx.x] += r1[threadIdx.x+st]; r2[threadIdx.x] += r2[threadIdx.x+st]; }
    __syncthreads();
  }
  if (threadIdx.x == 0){
    float m = r1[0] / (float)T;
    float var = r2[0] / (float)T - m*m;
    meanp[bc] = m;
    stdp[bc]  = sqrtf(var + EPS);
  }
}

__global__ __launch_bounds__(256) void k_norm(const float* __restrict__ query_in, const float* __restrict__ key_in,
                                              const float* __restrict__ revin_w, const float* __restrict__ revin_b,
                                              const float* __restrict__ meanp, const float* __restrict__ stdp,
                                              float* __restrict__ qn, float* __restrict__ kn){
  int idx = blockIdx.x*256 + threadIdx.x;
  int t = idx % T; int bc = idx / T;
  int c = bc % C;  int b = bc / C;
  float m = meanp[b*C + c];
  float inv = 1.f / stdp[b*C + c];
  float wv = revin_w[c], bv = revin_b[c];
  size_t src = ((size_t)(b*T) + t)*C + c;
  size_t dst = ((size_t)(b*C) + c)*XS + XPAD + t;
  qn[dst] = (query_in[src] - m) * inv * wv + bv;
  kn[dst] = (key_in[src]   - m) * inv * wv + bv;
}

// conv in: C=3 -> BN=32, k=15, dil=1, ReLU. grid = 3*B*BN, block = one (net,b,o) row.
// weights/bias indexed by blockIdx-derived o -> uniform -> s_load (no LDS for weights).
__global__ __launch_bounds__(256) void k_conv_in(
    const float* __restrict__ qn, const float* __restrict__ kn,
    const float* __restrict__ wq, const float* __restrict__ bq,
    const float* __restrict__ wk, const float* __restrict__ bk,
    const float* __restrict__ wv, const float* __restrict__ bv,
    float* __restrict__ hout){
  __shared__ float xs[C*XS];
  const int net = blockIdx.x / (B*BN);
  const int rem = blockIdx.x % (B*BN);
  const int b = rem / BN, o = rem % BN;
  const float* x    = (net==0 ? qn : kn) + (size_t)b*C*XS;
  const float* w    = (net==0 ? wq : (net==1 ? wk : wv)) + o*C*KW;
  const float* bias = (net==0 ? bq : (net==1 ? bk : bv));
  for (int i = threadIdx.x; i < C*XS; i += 256) xs[i] = x[i];
  __syncthreads();
  const float bo = bias[o];
  float* orow = hout + (((size_t)(net*B + b))*BN + o)*HS + HPAD;
  for (int j = 0; j < 8; j++){
    int t = j*256 + threadIdx.x;
    float acc = bo;
    #pragma unroll
    for (int c = 0; c < C; c++)
      #pragma unroll
      for (int kk = 0; kk < KW; kk++)
        acc += xs[c*XS + XPAD + t + kk - 7] * w[c*KW + kk];
    orow[t] = fmaxf(acc, 0.f);
  }
}

// dilated conv BN->BN, k=15, ReLU. grid = 3*8*32 = 768: (net, b, ttile of 64).
// wave -> o-octet (readfirstlane => weights via s_load, no LDS); lane -> t; thread = 8o x 1t.
template<int DIL>
__global__ __launch_bounds__(256) void k_conv_mid(
    const float* __restrict__ hin, float* __restrict__ hout,
    const float* __restrict__ wq, const float* __restrict__ wk, const float* __restrict__ wv,
    const float* __restrict__ bq, const float* __restrict__ bk, const float* __restrict__ bv,
    int layer){
  const int net = blockIdx.x >> 8;
  const int rem = blockIdx.x & 255;
  const int b = rem >> 5;
  const int tt = rem & 31;
  const int wave = __builtin_amdgcn_readfirstlane(threadIdx.x >> 6);
  const int lane = threadIdx.x & 63;
  const int t = tt*64 + lane;
  const float* w    = (net==0 ? wq : (net==1 ? wk : wv)) + (size_t)layer*BN*BN*KW + (size_t)wave*8*BN*KW;
  const float* bias = (net==0 ? bq : (net==1 ? bk : bv)) + layer*BN + wave*8;
  float acc[8] = {0.f,0.f,0.f,0.f,0.f,0.f,0.f,0.f};
  const float* xin = hin + ((size_t)(net*B + b))*BN*HS + HPAD + t - 7*DIL;
  for (int i = 0; i < BN; i++){
    const float* xr = xin + (size_t)i*HS;
    #pragma unroll
    for (int kk = 0; kk < KW; kk++){
      const float xv = xr[kk*DIL];
      #pragma unroll
      for (int r = 0; r < 8; r++)
        acc[r] += w[((size_t)r*BN + i)*KW + kk] * xv;
    }
  }
  float* op = hout + (((size_t)(net*B + b))*BN + wave*8)*HS + HPAD + t;
  #pragma unroll
  for (int r = 0; r < 8; r++)
    op[(size_t)r*HS] = fmaxf(acc[r] + bias[r], 0.f);
}

// 1x1 conv BN -> E, bf16 out; q pre-scaled by E^-0.5. grid = 3*8*16*4 = 1536.
// wave -> uniform 16-e group (readfirstlane), weights via s_load; thread = 16e x 2t.
__global__ __launch_bounds__(256) void k_conv_out(
    const float* __restrict__ hin,
    const float* __restrict__ wq, const float* __restrict__ bq,
    const float* __restrict__ wk, const float* __restrict__ bk,
    const float* __restrict__ wv, const float* __restrict__ bv,
    unsigned short* __restrict__ qo, unsigned short* __restrict__ ko, unsigned short* __restrict__ vo){
  const int net = blockIdx.x >> 9;
  const int rem = blockIdx.x & 511;
  const int b = rem >> 6;
  const int tt = (rem & 63) >> 2;
  const int eq = rem & 3;
  const int wave = __builtin_amdgcn_readfirstlane(threadIdx.x >> 6);
  const int lane = threadIdx.x & 63;
  const int t0 = tt*128 + lane*2;
  const int e_base = eq*64 + wave*16;
  const float* w    = (net==0 ? wq : (net==1 ? wk : wv)) + (size_t)e_base*BN;
  const float* bias = (net==0 ? bq : (net==1 ? bk : bv)) + e_base;
  float acc[16][2];
  #pragma unroll
  for (int j = 0; j < 16; j++){ acc[j][0] = 0.f; acc[j][1] = 0.f; }
  const float* hb = hin + (((size_t)(net*B + b))*BN)*HS + HPAD + t0;
  for (int i = 0; i < BN; i++){
    const float2 xv = *(const float2*)(hb + (size_t)i*HS);
    #pragma unroll
    for (int j = 0; j < 16; j++){
      const float wj = w[(size_t)j*BN + i];
      acc[j][0] += wj*xv.x; acc[j][1] += wj*xv.y;
    }
  }
  const float scale = (net==0) ? 0.0625f : 1.0f;
  unsigned short* outp = (net==0 ? qo : (net==1 ? ko : vo));
  #pragma unroll
  for (int z = 0; z < 2; z++){
    bfrag pk[2];
    #pragma unroll
    for (int j = 0; j < 16; j++)
      pk[j>>3][j&7] = f2bf((acc[j][z] + bias[j]) * scale);
    size_t dst = ((size_t)(b*T) + t0 + z)*E + e_base;
    *(bfrag*)&outp[dst]     = pk[0];
    *(bfrag*)&outp[dst + 8] = pk[1];
  }
}

// flash attention, BQ=128 (8 waves, 512 thr), BK=32, split-K=4. grid = B*16*4 = 512.
// threads 0-255 stage K, 256-511 stage V (transposed). partial O normalized bf16 + m,l.
// mfma_f32_16x16x32_bf16: A[m=l16][k=quad*8+j], B[k=quad*8+j][n=l16], D[row=quad*4+reg][col=l16].
__global__ __launch_bounds__(512, 4) void k_attn(
    const unsigned short* __restrict__ qbuf, const unsigned short* __restrict__ kbuf,
    const unsigned short* __restrict__ vbuf,
    unsigned short* __restrict__ PO_hi, unsigned short* __restrict__ PO_lo,
    float* __restrict__ MLm, float* __restrict__ MLl){
  __shared__ __align__(16) short Ks[32*264];    // K tile, key-major, e fast
  __shared__ __align__(16) short Vs[256*40];    // V^T tile, e-major, key fast
  __shared__ __align__(16) short Ps[8*16*40];   // per-wave P tile, row-major [q][key]

  const int s    = blockIdx.x & 3;
  const int qt   = (blockIdx.x >> 2) & 15;
  const int b    = blockIdx.x >> 6;
  const int tid  = threadIdx.x;
  const int wave = tid >> 6;
  const int lane = tid & 63;
  const int quad = lane >> 4;
  const int l16  = lane & 15;
  const int qrow_base = qt*128 + wave*16;

  bfrag a_q[8];
  {
    const unsigned short* qrow = qbuf + ((size_t)(b*T) + qrow_base + l16)*E + quad*8;
    #pragma unroll
    for (int kt = 0; kt < 8; kt++)
      a_q[kt] = *(const bfrag*)&qrow[kt*32];
  }

  f32x4 acc_o[16];
  #pragma unroll
  for (int nt = 0; nt < 16; nt++){ f32x4 z = {0.f,0.f,0.f,0.f}; acc_o[nt] = z; }
  float m_run[4] = {-1e30f,-1e30f,-1e30f,-1e30f};
  float l_run[4] = {0.f,0.f,0.f,0.f};

  const int jk = tid >> 3;           // K staging row (K-threads)
  const int ec = (tid & 7) * 32;
  const int ev = tid - 256;          // V staging column (V-threads)

  for (int kbk = s*16; kbk < s*16 + 16; kbk++){
    const int j0 = kbk*32;
    if (tid < 256){
      const unsigned short* krow = kbuf + ((size_t)(b*T) + j0 + jk)*E + ec;
      #pragma unroll
      for (int u = 0; u < 4; u++)
        *(bfrag*)&Ks[jk*264 + ec + u*8] = *(const bfrag*)&krow[u*8];
    } else {
      const unsigned short* vcol = vbuf + ((size_t)(b*T) + j0)*E + ev;
      #pragma unroll
      for (int u = 0; u < 4; u++){
        bfrag p;
        #pragma unroll
        for (int z = 0; z < 8; z++) p[z] = (short)vcol[(size_t)(u*8+z)*E];
        *(bfrag*)&Vs[ev*40 + u*8] = p;
      }
    }
    __syncthreads();

    // S = Q K^T (two 4-deep chains per 16-key half)
    f32x4 s0a = {0,0,0,0}, s0b = {0,0,0,0}, s1a = {0,0,0,0}, s1b = {0,0,0,0};
    #pragma unroll
    for (int kt = 0; kt < 8; kt += 2){
      bfrag k0a = *(const bfrag*)&Ks[(l16     )*264 + kt*32 + quad*8];
      bfrag k1a = *(const bfrag*)&Ks[(16 + l16)*264 + kt*32 + quad*8];
      bfrag k0b = *(const bfrag*)&Ks[(l16     )*264 + (kt+1)*32 + quad*8];
      bfrag k1b = *(const bfrag*)&Ks[(16 + l16)*264 + (kt+1)*32 + quad*8];
      s0a = __builtin_amdgcn_mfma_f32_16x16x32_bf16(a_q[kt],   k0a, s0a, 0, 0, 0);
      s1a = __builtin_amdgcn_mfma_f32_16x16x32_bf16(a_q[kt],   k1a, s1a, 0, 0, 0);
      s0b = __builtin_amdgcn_mfma_f32_16x16x32_bf16(a_q[kt+1], k0b, s0b, 0, 0, 0);
      s1b = __builtin_amdgcn_mfma_f32_16x16x32_bf16(a_q[kt+1], k1b, s1b, 0, 0, 0);
    }
    f32x4 sac0 = s0a + s0b, sac1 = s1a + s1b;

    // online softmax (rows = quad*4+rr, cols = l16 / 16+l16)
    float mloc[4], lloc[4], p0[4], p1[4], alpha[4];
    #pragma unroll
    for (int rr = 0; rr < 4; rr++) mloc[rr] = fmaxf(sac0[rr], sac1[rr]);
    #pragma unroll
    for (int off = 1; off < 16; off <<= 1)
      #pragma unroll
      for (int rr = 0; rr < 4; rr++) mloc[rr] = fmaxf(mloc[rr], __shfl_xor(mloc[rr], off));
    int upd = 0;
    #pragma unroll
    for (int rr = 0; rr < 4; rr++) upd |= (mloc[rr] > m_run[rr]);
    #pragma unroll
    for (int rr = 0; rr < 4; rr++){
      float mn = fmaxf(m_run[rr], mloc[rr]);
      alpha[rr] = __expf(m_run[rr] - mn);
      p0[rr] = __expf(sac0[rr] - mn);
      p1[rr] = __expf(sac1[rr] - mn);
      lloc[rr] = p0[rr] + p1[rr];
      m_run[rr] = mn;
    }
    #pragma unroll
    for (int off = 1; off < 16; off <<= 1)
      #pragma unroll
      for (int rr = 0; rr < 4; rr++) lloc[rr] += __shfl_xor(lloc[rr], off);
    #pragma unroll
    for (int rr = 0; rr < 4; rr++) l_run[rr] = l_run[rr]*alpha[rr] + lloc[rr];
    // P -> per-wave LDS (same wave writes & reads; no barrier)
    #pragma unroll
    for (int rr = 0; rr < 4; rr++){
      Ps[wave*640 + (quad*4+rr)*40 + l16]      = f2bf(p0[rr]);
      Ps[wave*640 + (quad*4+rr)*40 + 16 + l16] = f2bf(p1[rr]);
    }
    // rescale O only if some row's max moved (wave-uniform skip)
    if (__ballot(upd)){
      #pragma unroll
      for (int nt = 0; nt < 16; nt++)
        #pragma unroll
        for (int rr = 0; rr < 4; rr++) acc_o[nt][rr] *= alpha[rr];
    }

    // O += P V
    bfrag pa = *(const bfrag*)&Ps[wave*640 + l16*40 + quad*8];
    #pragma unroll
    for (int nt = 0; nt < 16; nt++){
      bfrag vf = *(const bfrag*)&Vs[(nt*16 + l16)*40 + quad*8];
      acc_o[nt] = __builtin_amdgcn_mfma_f32_16x16x32_bf16(pa, vf, acc_o[nt], 0, 0, 0);
    }
    __syncthreads();
  }

  // epilogue: store normalized partial O (bf16) + m,l
  unsigned short* PO = (s < 3) ? (PO_hi + (size_t)s*((size_t)B*T*E)) : PO_lo;
  #pragma unroll
  for (int rr = 0; rr < 4; rr++){
    float inv_l = 1.f / l_run[rr];
    const int row = qrow_base + quad*4 + rr;
    const size_t off = ((size_t)(b*T) + row)*E;
    #pragma unroll
    for (int nt = 0; nt < 16; nt++)
      PO[off + nt*16 + l16] = (unsigned short)f2bf(acc_o[nt][rr] * inv_l);
    if (l16 == 0){
      const size_t rm = ((size_t)(s*B + b))*T + row;
      MLm[rm] = m_run[rr];
      MLl[rm] = l_run[rr];
    }
  }
}

// combine 4 splits + out-projection + RevIN denorm. grid = B*T/32 = 512, 256 thr.
__global__ __launch_bounds__(256) void k_comb(
    const unsigned short* __restrict__ PO_hi, const unsigned short* __restrict__ PO_lo,
    const float* __restrict__ MLm, const float* __restrict__ MLl,
    const float* __restrict__ out_w, const float* __restrict__ out_b,
    const float* __restrict__ revin_w, const float* __restrict__ revin_b,
    const float* __restrict__ meanp, const float* __restrict__ stdp,
    float* __restrict__ out){
  __shared__ float wsh[3*E];
  for (int i = threadIdx.x; i < 3*E; i += 256) wsh[i] = out_w[i];
  __syncthreads();
  const int b  = blockIdx.x >> 6;
  const int rt = blockIdx.x & 63;
  const int row = rt*32 + (threadIdx.x >> 3);
  const int c8 = threadIdx.x & 7;
  const int e0 = c8*32;
  float ms[4], ls[4], wn[4];
  #pragma unroll
  for (int s2 = 0; s2 < 4; s2++){
    const size_t rm = ((size_t)(s2*B + b))*T + row;
    ms[s2] = MLm[rm]; ls[s2] = MLl[rm];
  }
  float mx = fmaxf(fmaxf(ms[0], ms[1]), fmaxf(ms[2], ms[3]));
  float wsum = 0.f;
  #pragma unroll
  for (int s2 = 0; s2 < 4; s2++){ wn[s2] = __expf(ms[s2]-mx)*ls[s2]; wsum += wn[s2]; }
  float inv = 1.f/wsum;
  #pragma unroll
  for (int s2 = 0; s2 < 4; s2++) wn[s2] *= inv;
  const unsigned short* ps[4];
  #pragma unroll
  for (int s2 = 0; s2 < 4; s2++){
    const unsigned short* base = (s2 < 3) ? (PO_hi + (size_t)s2*((size_t)B*T*E)) : PO_lo;
    ps[s2] = base + ((size_t)(b*T) + row)*E + e0;
  }
  float pr[3] = {0.f, 0.f, 0.f};
  #pragma unroll
  for (int u = 0; u < 4; u++){
    float v[8] = {0,0,0,0,0,0,0,0};
    #pragma unroll
    for (int s2 = 0; s2 < 4; s2++){
      bfrag a = *(const bfrag*)&ps[s2][u*8];
      #pragma unroll
      for (int z = 0; z < 8; z++) v[z] += wn[s2]*bf2f((unsigned short)a[z]);
    }
    #pragma unroll
    for (int z = 0; z < 8; z++){
      int e = e0 + u*8 + z;
      pr[0] += v[z]*wsh[e];
      pr[1] += v[z]*wsh[E + e];
      pr[2] += v[z]*wsh[2*E + e];
    }
  }
  #pragma unroll
  for (int c = 0; c < 3; c++){
    pr[c] += __shfl_xor(pr[c], 1);
    pr[c] += __shfl_xor(pr[c], 2);
    pr[c] += __shfl_xor(pr[c], 4);
  }
  if (c8 == 0){
    #pragma unroll
    for (int c = 0; c < 3; c++){
      float val = pr[c] + out_b[c];
      val = (val - revin_b[c]) / revin_w[c];
      val = val * stdp[b*C + c] + meanp[b*C + c];
      out[((size_t)(b*T) + row)*C + c] = val;
    }
  }
}

} // namespace

extern "C" void kernel_launch(void* const* d_in, const int* in_sizes, int n_in,
                              void* d_out, int out_size, void* d_ws, size_t ws_size,
                              hipStream_t stream){
  const float* query_in = (const float*)d_in[0];
  const float* key_in   = (const float*)d_in[1];
  const float* q_w_in   = (const float*)d_in[2];
  const float* q_b_in   = (const float*)d_in[3];
  const float* q_w_mid  = (const float*)d_in[4];
  const float* q_b_mid  = (const float*)d_in[5];
  const float* q_w_out  = (const float*)d_in[6];
  const float* q_b_out  = (const float*)d_in[7];
  const float* k_w_in   = (const float*)d_in[8];
  const float* k_b_in   = (const float*)d_in[9];
  const float* k_w_mid  = (const float*)d_in[10];
  const float* k_b_mid  = (const float*)d_in[11];
  const float* k_w_out  = (const float*)d_in[12];
  const float* k_b_out  = (const float*)d_in[13];
  const float* v_w_in   = (const float*)d_in[14];
  const float* v_b_in   = (const float*)d_in[15];
  const float* v_w_mid  = (const float*)d_in[16];
  const float* v_b_mid  = (const float*)d_in[17];
  const float* v_w_out  = (const float*)d_in[18];
  const float* v_b_out  = (const float*)d_in[19];
  const float* out_w    = (const float*)d_in[20];
  const float* out_b    = (const float*)d_in[21];
  const float* revin_w  = (const float*)d_in[22];
  const float* revin_b  = (const float*)d_in[23];
  float* ws  = (float*)d_ws;
  float* out = (float*)d_out;

  unsigned short* qb = (unsigned short*)(ws + O_Q);
  unsigned short* kb = (unsigned short*)(ws + O_K);
  unsigned short* vb = (unsigned short*)(ws + O_V);
  unsigned short* PO_hi = (unsigned short*)(ws + O_PO_HI);
  unsigned short* PO_lo = (unsigned short*)(ws + O_PO_LO);
  float* MLm = ws + O_MLM;
  float* MLl = ws + O_MLL;

  hipLaunchKernelGGL(k_zero, dim3(2048), dim3(256), 0, stream, (float4*)ws, (int)(O_Q/4));
  hipLaunchKernelGGL(k_stats, dim3(B*C), dim3(256), 0, stream, key_in, ws+O_MEAN, ws+O_STD);
  hipLaunchKernelGGL(k_norm, dim3((B*C*T)/256), dim3(256), 0, stream,
                     query_in, key_in, revin_w, revin_b, ws+O_MEAN, ws+O_STD, ws+O_QN, ws+O_KN);
  hipLaunchKernelGGL(k_conv_in, dim3(3*B*BN), dim3(256), 0, stream,
                     ws+O_QN, ws+O_KN, q_w_in, q_b_in, k_w_in, k_b_in, v_w_in, v_b_in, ws+O_HA);
  float* ha = ws + O_HA;
  float* hb = ws + O_HB;
  hipLaunchKernelGGL(k_conv_mid<2>,  dim3(768), dim3(256), 0, stream, ha, hb,
                     q_w_mid, k_w_mid, v_w_mid, q_b_mid, k_b_mid, v_b_mid, 0);
  hipLaunchKernelGGL(k_conv_mid<4>,  dim3(768), dim3(256), 0, stream, hb, ha,
                     q_w_mid, k_w_mid, v_w_mid, q_b_mid, k_b_mid, v_b_mid, 1);
  hipLaunchKernelGGL(k_conv_mid<8>,  dim3(768), dim3(256), 0, stream, ha, hb,
                     q_w_mid, k_w_mid, v_w_mid, q_b_mid, k_b_mid, v_b_mid, 2);
  hipLaunchKernelGGL(k_conv_mid<16>, dim3(768), dim3(256), 0, stream, hb, ha,
                     q_w_mid, k_w_mid, v_w_mid, q_b_mid, k_b_mid, v_b_mid, 3);
  hipLaunchKernelGGL(k_conv_mid<32>, dim3(768), dim3(256), 0, stream, ha, hb,
                     q_w_mid, k_w_mid, v_w_mid, q_b_mid, k_b_mid, v_b_mid, 4);
  hipLaunchKernelGGL(k_conv_out, dim3(1536), dim3(256), 0, stream,
                     hb, q_w_out, q_b_out, k_w_out, k_b_out, v_w_out, v_b_out, qb, kb, vb);
  hipLaunchKernelGGL(k_attn, dim3(B*16*4), dim3(512), 0, stream, qb, kb, vb, PO_hi, PO_lo, MLm, MLl);
  hipLaunchKernelGGL(k_comb, dim3(B*T/32), dim3(256), 0, stream,
                     PO_hi, PO_lo, MLm, MLl, out_w, out_b, revin_w, revin_b, ws+O_MEAN, ws+O_STD, out);
}